// Round 1
// baseline (2425.050 us; speedup 1.0000x reference)
//
#include <hip/hip_runtime.h>
#include <math.h>

#define NN 100000
#define FIN 500
#define HIDN 64
#define KF 5
#define DORD 10

struct Tables { float sinc[KF][DORD+1]; float cosc[KF][DORD+1]; };

// ---- coeff[d] = sum_k alpha[k]*sinc[k][d] + beta[k]*cosc[k][d] ----
__global__ void coeff_kernel(const float* __restrict__ alpha, const float* __restrict__ beta,
                             Tables tb, float* __restrict__ coeff) {
    int d = threadIdx.x;
    if (d <= DORD) {
        float c = 0.f;
        #pragma unroll
        for (int k = 0; k < KF; ++k)
            c += alpha[k] * tb.sinc[k][d] + beta[k] * tb.cosc[k][d];
        coeff[d] = c;
    }
}

// ---- degree counting (out-deg by src for dinv, in-deg by dst for CSR) ----
__global__ void count_kernel(const int* __restrict__ src, const int* __restrict__ dst,
                             int* __restrict__ deg, int* __restrict__ indeg, int E) {
    int e = blockIdx.x * blockDim.x + threadIdx.x;
    if (e >= E) return;
    int s = src[e], d = dst[e];
    if (s != d) { atomicAdd(&deg[s], 1); atomicAdd(&indeg[d], 1); }
}

__global__ void dinv_kernel(const int* __restrict__ deg, float* __restrict__ dinv, int n) {
    int i = blockIdx.x * blockDim.x + threadIdx.x;
    if (i >= n) return;
    int d = deg[i];
    dinv[i] = (d > 0) ? (1.0f / sqrtf((float)d)) : 0.f;
}

// ---- single-block exclusive scan of indeg -> row_ptr (+cursor copy) ----
__global__ void scan_kernel(const int* __restrict__ indeg, int* __restrict__ row_ptr,
                            int* __restrict__ cursor, int n) {
    __shared__ int part[1024];
    int t = threadIdx.x;
    int chunk = (n + 1023) >> 10;
    int lo = t * chunk;
    int hi = lo + chunk; if (hi > n) hi = n;
    int s = 0;
    for (int i = lo; i < hi; ++i) s += indeg[i];
    part[t] = s;
    __syncthreads();
    for (int off = 1; off < 1024; off <<= 1) {
        int add = (t >= off) ? part[t - off] : 0;
        __syncthreads();
        part[t] += add;
        __syncthreads();
    }
    int run = (t > 0) ? part[t - 1] : 0;
    for (int i = lo; i < hi; ++i) {
        row_ptr[i] = run; cursor[i] = run;
        run += indeg[i];
    }
    if (t == 1023) row_ptr[n] = part[1023];
}

// ---- scatter edges into dst-CSR with edge weight -(dinv[s]*dinv[d]) ----
__global__ void fill_kernel(const int* __restrict__ src, const int* __restrict__ dst,
                            const float* __restrict__ dinv, int* __restrict__ cursor,
                            int* __restrict__ col, float* __restrict__ wedge, int E) {
    int e = blockIdx.x * blockDim.x + threadIdx.x;
    if (e >= E) return;
    int s = src[e], d = dst[e];
    if (s == d) return;
    float w = -(dinv[s] * dinv[d]);
    int pos = atomicAdd(&cursor[d], 1);
    col[pos] = s;
    wedge[pos] = w;
}

// ---- GEMM1: H = relu(A[n,500] @ W[500,64] + b) ----
__global__ __launch_bounds__(256) void gemm1_kernel(
    const float* __restrict__ A, const float* __restrict__ W,
    const float* __restrict__ bias, float* __restrict__ H, int n) {
    __shared__ float sA[64][36];   // row-major A tile, padded
    __shared__ float sW[32][64];
    int t = threadIdx.x;
    int tx = t & 15, ty = t >> 4;
    int rowBase = blockIdx.x * 64;
    float acc[4][4] = {{0.f}};
    for (int k0 = 0; k0 < FIN; k0 += 32) {
        #pragma unroll
        for (int l = 0; l < 2; ++l) {
            int c = t + l * 256;              // 512 float4 chunks for A tile
            int r = c >> 3, cc = (c & 7) * 4;
            int gr = rowBase + r, gk = k0 + cc;
            float4 v = make_float4(0.f, 0.f, 0.f, 0.f);
            if (gr < n && gk < FIN) v = *(const float4*)(A + (size_t)gr * FIN + gk);
            *(float4*)&sA[r][cc] = v;
        }
        #pragma unroll
        for (int l = 0; l < 2; ++l) {
            int c = t + l * 256;              // 512 float4 chunks for W tile
            int r = c >> 4, cc = (c & 15) * 4;
            int gk = k0 + r;
            float4 v = make_float4(0.f, 0.f, 0.f, 0.f);
            if (gk < FIN) v = *(const float4*)(W + (size_t)gk * 64 + cc);
            *(float4*)&sW[r][cc] = v;
        }
        __syncthreads();
        #pragma unroll
        for (int kk = 0; kk < 32; ++kk) {
            float a[4], b[4];
            #pragma unroll
            for (int i = 0; i < 4; ++i) a[i] = sA[ty * 4 + i][kk];
            #pragma unroll
            for (int j = 0; j < 4; ++j) b[j] = sW[kk][tx * 4 + j];
            #pragma unroll
            for (int i = 0; i < 4; ++i)
                #pragma unroll
                for (int j = 0; j < 4; ++j)
                    acc[i][j] = fmaf(a[i], b[j], acc[i][j]);
        }
        __syncthreads();
    }
    #pragma unroll
    for (int i = 0; i < 4; ++i) {
        int gr = rowBase + ty * 4 + i;
        if (gr < n) {
            float4 o;
            o.x = fmaxf(acc[i][0] + bias[tx * 4 + 0], 0.f);
            o.y = fmaxf(acc[i][1] + bias[tx * 4 + 1], 0.f);
            o.z = fmaxf(acc[i][2] + bias[tx * 4 + 2], 0.f);
            o.w = fmaxf(acc[i][3] + bias[tx * 4 + 3], 0.f);
            *(float4*)(H + (size_t)gr * 64 + tx * 4) = o;
        }
    }
}

// ---- GEMM2: X = H @ W2 + b2 ; out = (1+coeff[0]) * X ----
__global__ __launch_bounds__(256) void gemm2_kernel(
    const float* __restrict__ H, const float* __restrict__ W2,
    const float* __restrict__ b2, const float* __restrict__ coeff,
    float* __restrict__ X, float* __restrict__ out, int n) {
    __shared__ float sW[64 * 64];
    __shared__ float sb[64];
    int t = threadIdx.x;
    for (int i = t; i < 4096; i += 256) sW[i] = W2[i];
    if (t < 64) sb[t] = b2[t];
    __syncthreads();
    float c0p1 = 1.f + coeff[0];
    int lane = t & 63;
    int wid = t >> 6;
    int r0 = blockIdx.x * 128;
    int rend = r0 + 128; if (rend > n) rend = n;
    for (int r = r0 + wid; r < rend; r += 4) {
        float hv = H[(size_t)r * 64 + lane];
        float acc = sb[lane];
        #pragma unroll
        for (int k = 0; k < 64; ++k)
            acc = fmaf(__shfl(hv, k, 64), sW[k * 64 + lane], acc);
        X[(size_t)r * 64 + lane] = acc;
        out[(size_t)r * 64 + lane] = c0p1 * acc;
    }
}

// ---- SpMM hop: one wave per dst row; fused hidden accumulate into out ----
__global__ __launch_bounds__(256) void spmm_kernel(
    const int* __restrict__ row_ptr, const int* __restrict__ col,
    const float* __restrict__ wedge, const float* __restrict__ tin,
    float* __restrict__ tout, float* __restrict__ out,
    const float* __restrict__ coeff, int d, int n) {
    int wave = (blockIdx.x * blockDim.x + threadIdx.x) >> 6;
    int lane = threadIdx.x & 63;
    if (wave >= n) return;
    int e0 = row_ptr[wave], e1 = row_ptr[wave + 1];
    float acc = 0.f;
    int e = e0;
    for (; e + 3 < e1; e += 4) {
        int s0 = col[e], s1 = col[e + 1], s2 = col[e + 2], s3 = col[e + 3];
        float w0 = wedge[e], w1 = wedge[e + 1], w2 = wedge[e + 2], w3 = wedge[e + 3];
        float v0 = tin[(size_t)s0 * 64 + lane];
        float v1 = tin[(size_t)s1 * 64 + lane];
        float v2 = tin[(size_t)s2 * 64 + lane];
        float v3 = tin[(size_t)s3 * 64 + lane];
        acc = fmaf(w0, v0, acc);
        acc = fmaf(w1, v1, acc);
        acc = fmaf(w2, v2, acc);
        acc = fmaf(w3, v3, acc);
    }
    for (; e < e1; ++e)
        acc = fmaf(wedge[e], tin[(size_t)col[e] * 64 + lane], acc);
    tout[(size_t)wave * 64 + lane] = acc;
    out[(size_t)wave * 64 + lane] += coeff[d] * acc;
}

// ---- log_softmax over rows of 64 ----
__global__ __launch_bounds__(256) void lsm_kernel(float* __restrict__ out, int n) {
    int wave = (blockIdx.x * blockDim.x + threadIdx.x) >> 6;
    int lane = threadIdx.x & 63;
    if (wave >= n) return;
    float v = out[(size_t)wave * 64 + lane];
    float m = v;
    #pragma unroll
    for (int o = 32; o; o >>= 1) m = fmaxf(m, __shfl_xor(m, o, 64));
    float ex = expf(v - m);
    float ssum = ex;
    #pragma unroll
    for (int o = 32; o; o >>= 1) ssum += __shfl_xor(ssum, o, 64);
    out[(size_t)wave * 64 + lane] = v - m - logf(ssum);
}

extern "C" void kernel_launch(void* const* d_in, const int* in_sizes, int n_in,
                              void* d_out, int out_size, void* d_ws, size_t ws_size,
                              hipStream_t stream) {
    const float* feature = (const float*)d_in[0];
    const int*   edges   = (const int*)d_in[1];
    const float* W1      = (const float*)d_in[2];
    const float* b1      = (const float*)d_in[3];
    const float* W2      = (const float*)d_in[4];
    const float* b2      = (const float*)d_in[5];
    const float* alpha   = (const float*)d_in[6];
    const float* beta    = (const float*)d_in[7];
    float* out = (float*)d_out;

    const int n = in_sizes[0] / FIN;      // 100000
    const int E = in_sizes[1] / 2;        // 3200000
    const int* src = edges;
    const int* dst = edges + E;

    // ---- workspace layout (256B aligned) ----
    char* ws = (char*)d_ws;
    size_t off = 0;
    auto alloc = [&](size_t bytes) { size_t o = off; off = (off + bytes + 255) & ~(size_t)255; return o; };
    float* coeff   = (float*)(ws + alloc(64 * 4));
    int*   deg     = (int*)  (ws + alloc((size_t)n * 4));
    int*   indeg   = (int*)  (ws + alloc((size_t)n * 4));
    float* dinv    = (float*)(ws + alloc((size_t)n * 4));
    int*   row_ptr = (int*)  (ws + alloc(((size_t)n + 1) * 4));
    int*   cursor  = (int*)  (ws + alloc((size_t)n * 4));
    int*   col     = (int*)  (ws + alloc((size_t)E * 4));
    float* wedge   = (float*)(ws + alloc((size_t)E * 4));
    float* X       = (float*)(ws + alloc((size_t)n * 64 * 4));
    float* TxA     = (float*)(ws + alloc((size_t)n * 64 * 4));
    float* TxB     = (float*)(ws + alloc((size_t)n * 64 * 4));
    float* H = TxA;   // alias: H consumed by gemm2 before hop 1 writes TxA

    // ---- host-side Taylor tables (deterministic, recomputed every call) ----
    Tables tb;
    for (int k = 0; k < KF; ++k) {
        double x = M_PI * (double)(k + 1);   // OMEGA = 1
        double p = 1.0, f = 1.0;
        for (int o = 0; o <= DORD; ++o) {
            if (o > 0) { p *= x; f *= (double)o; }
            double v = p / f;
            tb.cosc[k][o] = (o % 2 == 0) ? (float)((((o / 2) % 2 == 0) ? 1.0 : -1.0) * v) : 0.f;
            tb.sinc[k][o] = (o % 2 == 1) ? (float)(((((o - 1) / 2) % 2 == 0) ? 1.0 : -1.0) * v) : 0.f;
        }
    }

    hipMemsetAsync(deg, 0, (size_t)n * 4, stream);
    hipMemsetAsync(indeg, 0, (size_t)n * 4, stream);

    coeff_kernel<<<1, 64, 0, stream>>>(alpha, beta, tb, coeff);
    count_kernel<<<(E + 255) / 256, 256, 0, stream>>>(src, dst, deg, indeg, E);
    dinv_kernel<<<(n + 255) / 256, 256, 0, stream>>>(deg, dinv, n);
    scan_kernel<<<1, 1024, 0, stream>>>(indeg, row_ptr, cursor, n);
    fill_kernel<<<(E + 255) / 256, 256, 0, stream>>>(src, dst, dinv, cursor, col, wedge, E);

    gemm1_kernel<<<(n + 63) / 64, 256, 0, stream>>>(feature, W1, b1, H, n);
    gemm2_kernel<<<(n + 127) / 128, 256, 0, stream>>>(H, W2, b2, coeff, X, out, n);

    const float* tin = X;
    float* bufs[2] = { TxA, TxB };
    for (int d = 1; d <= DORD; ++d) {
        float* tout = bufs[(d - 1) & 1];
        spmm_kernel<<<(n + 3) / 4, 256, 0, stream>>>(row_ptr, col, wedge, tin, tout, out, coeff, d, n);
        tin = tout;
    }

    lsm_kernel<<<(n + 3) / 4, 256, 0, stream>>>(out, n);
}

// Round 2
// 2275.776 us; speedup vs baseline: 1.0656x; 1.0656x over previous
//
#include <hip/hip_runtime.h>
#include <math.h>

#define NN 100000
#define FIN 500
#define HIDN 64
#define KF 5
#define DORD 10

struct Tables { float sinc[KF][DORD+1]; float cosc[KF][DORD+1]; };

// ---- coeff[d] = sum_k alpha[k]*sinc[k][d] + beta[k]*cosc[k][d] ----
__global__ void coeff_kernel(const float* __restrict__ alpha, const float* __restrict__ beta,
                             Tables tb, float* __restrict__ coeff) {
    int d = threadIdx.x;
    if (d <= DORD) {
        float c = 0.f;
        #pragma unroll
        for (int k = 0; k < KF; ++k)
            c += alpha[k] * tb.sinc[k][d] + beta[k] * tb.cosc[k][d];
        coeff[d] = c;
    }
}

// ---- degree counting (out-deg by src for dinv, in-deg by dst for CSR) ----
__global__ void count_kernel(const int* __restrict__ src, const int* __restrict__ dst,
                             int* __restrict__ deg, int* __restrict__ indeg, int E) {
    int e = blockIdx.x * blockDim.x + threadIdx.x;
    if (e >= E) return;
    int s = src[e], d = dst[e];
    if (s != d) { atomicAdd(&deg[s], 1); atomicAdd(&indeg[d], 1); }
}

__global__ void dinv_kernel(const int* __restrict__ deg, float* __restrict__ dinv, int n) {
    int i = blockIdx.x * blockDim.x + threadIdx.x;
    if (i >= n) return;
    int d = deg[i];
    dinv[i] = (d > 0) ? (1.0f / sqrtf((float)d)) : 0.f;
}

// ---- single-block exclusive scan of indeg -> row_ptr (+cursor copy) ----
__global__ void scan_kernel(const int* __restrict__ indeg, int* __restrict__ row_ptr,
                            int* __restrict__ cursor, int n) {
    __shared__ int part[1024];
    int t = threadIdx.x;
    int chunk = (n + 1023) >> 10;
    int lo = t * chunk;
    int hi = lo + chunk; if (hi > n) hi = n;
    int s = 0;
    for (int i = lo; i < hi; ++i) s += indeg[i];
    part[t] = s;
    __syncthreads();
    for (int off = 1; off < 1024; off <<= 1) {
        int add = (t >= off) ? part[t - off] : 0;
        __syncthreads();
        part[t] += add;
        __syncthreads();
    }
    int run = (t > 0) ? part[t - 1] : 0;
    for (int i = lo; i < hi; ++i) {
        row_ptr[i] = run; cursor[i] = run;
        run += indeg[i];
    }
    if (t == 1023) row_ptr[n] = part[1023];
}

// ---- scatter edges into dst-CSR (col only; weights folded into dinv state) ----
__global__ void fill_kernel(const int* __restrict__ src, const int* __restrict__ dst,
                            int* __restrict__ cursor, int* __restrict__ col, int E) {
    int e = blockIdx.x * blockDim.x + threadIdx.x;
    if (e >= E) return;
    int s = src[e], d = dst[e];
    if (s == d) return;
    int pos = atomicAdd(&cursor[d], 1);
    col[pos] = s;
}

// ---- GEMM1: H = relu(A[n,500] @ W[500,64] + b) ----
__global__ __launch_bounds__(256) void gemm1_kernel(
    const float* __restrict__ A, const float* __restrict__ W,
    const float* __restrict__ bias, float* __restrict__ H, int n) {
    __shared__ float sA[64][36];   // row-major A tile, padded
    __shared__ float sW[32][64];
    int t = threadIdx.x;
    int tx = t & 15, ty = t >> 4;
    int rowBase = blockIdx.x * 64;
    float acc[4][4] = {{0.f}};
    for (int k0 = 0; k0 < FIN; k0 += 32) {
        #pragma unroll
        for (int l = 0; l < 2; ++l) {
            int c = t + l * 256;
            int r = c >> 3, cc = (c & 7) * 4;
            int gr = rowBase + r, gk = k0 + cc;
            float4 v = make_float4(0.f, 0.f, 0.f, 0.f);
            if (gr < n && gk < FIN) v = *(const float4*)(A + (size_t)gr * FIN + gk);
            *(float4*)&sA[r][cc] = v;
        }
        #pragma unroll
        for (int l = 0; l < 2; ++l) {
            int c = t + l * 256;
            int r = c >> 4, cc = (c & 15) * 4;
            int gk = k0 + r;
            float4 v = make_float4(0.f, 0.f, 0.f, 0.f);
            if (gk < FIN) v = *(const float4*)(W + (size_t)gk * 64 + cc);
            *(float4*)&sW[r][cc] = v;
        }
        __syncthreads();
        #pragma unroll
        for (int kk = 0; kk < 32; ++kk) {
            float a[4], b[4];
            #pragma unroll
            for (int i = 0; i < 4; ++i) a[i] = sA[ty * 4 + i][kk];
            #pragma unroll
            for (int j = 0; j < 4; ++j) b[j] = sW[kk][tx * 4 + j];
            #pragma unroll
            for (int i = 0; i < 4; ++i)
                #pragma unroll
                for (int j = 0; j < 4; ++j)
                    acc[i][j] = fmaf(a[i], b[j], acc[i][j]);
        }
        __syncthreads();
    }
    #pragma unroll
    for (int i = 0; i < 4; ++i) {
        int gr = rowBase + ty * 4 + i;
        if (gr < n) {
            float4 o;
            o.x = fmaxf(acc[i][0] + bias[tx * 4 + 0], 0.f);
            o.y = fmaxf(acc[i][1] + bias[tx * 4 + 1], 0.f);
            o.z = fmaxf(acc[i][2] + bias[tx * 4 + 2], 0.f);
            o.w = fmaxf(acc[i][3] + bias[tx * 4 + 3], 0.f);
            *(float4*)(H + (size_t)gr * 64 + tx * 4) = o;
        }
    }
}

// ---- GEMM2: X = H @ W2 + b2 ; out = (1+coeff[0])*X ; ty0 = dinv ⊙ X ----
__global__ __launch_bounds__(256) void gemm2_kernel(
    const float* __restrict__ H, const float* __restrict__ W2,
    const float* __restrict__ b2, const float* __restrict__ coeff,
    const float* __restrict__ dinv, float* __restrict__ ty0,
    float* __restrict__ out, int n) {
    __shared__ float sW[64 * 64];
    __shared__ float sb[64];
    int t = threadIdx.x;
    for (int i = t; i < 4096; i += 256) sW[i] = W2[i];
    if (t < 64) sb[t] = b2[t];
    __syncthreads();
    float c0p1 = 1.f + coeff[0];
    int lane = t & 63;
    int wid = t >> 6;
    int r0 = blockIdx.x * 128;
    int rend = r0 + 128; if (rend > n) rend = n;
    for (int r = r0 + wid; r < rend; r += 4) {
        float hv = H[(size_t)r * 64 + lane];
        float dr = dinv[r];
        float acc = sb[lane];
        #pragma unroll
        for (int k = 0; k < 64; ++k)
            acc = fmaf(__shfl(hv, k, 64), sW[k * 64 + lane], acc);
        ty0[(size_t)r * 64 + lane] = dr * acc;
        out[(size_t)r * 64 + lane] = c0p1 * acc;
    }
}

// ---- SpMM hop (dinv-folded): one wave per dst row, 16 lanes x float4 per
// source row so one wave-instruction gathers 4 edges (1 KB in flight);
// unroll 4 -> up to 4 KB outstanding per wave.
// Ty = dinv ⊙ Tx.  Tx_new[r] = -dinv[r] * Σ_{s∈N(r)} Ty[s]
// tyout[r] = dinv[r]*Tx_new[r];  out[r] += coeff[d]*Tx_new[r]
// fuse_lsm: final hop applies log_softmax to out instead of writing tyout.
__global__ __launch_bounds__(256) void spmm_kernel(
    const int* __restrict__ row_ptr, const int* __restrict__ col,
    const float* __restrict__ dinv, const float* __restrict__ tyin,
    float* __restrict__ tyout, float* __restrict__ out,
    const float* __restrict__ coeff, int d, int n, int fuse_lsm) {
    int wave = (blockIdx.x * blockDim.x + threadIdx.x) >> 6;
    if (wave >= n) return;
    int lane = threadIdx.x & 63;
    int sub = lane >> 4;       // 0..3: which edge within a group of 4
    int fl = lane & 15;        // feature group: floats 4*fl .. 4*fl+3
    int e0 = row_ptr[wave], e1 = row_ptr[wave + 1];
    float ax = 0.f, ay = 0.f, az = 0.f, aw = 0.f;
    int e = e0 + sub;
    for (; e + 12 < e1; e += 16) {
        int s0 = col[e], s1 = col[e + 4], s2 = col[e + 8], s3 = col[e + 12];
        float4 v0 = *(const float4*)(tyin + (size_t)s0 * 64 + fl * 4);
        float4 v1 = *(const float4*)(tyin + (size_t)s1 * 64 + fl * 4);
        float4 v2 = *(const float4*)(tyin + (size_t)s2 * 64 + fl * 4);
        float4 v3 = *(const float4*)(tyin + (size_t)s3 * 64 + fl * 4);
        ax += (v0.x + v1.x) + (v2.x + v3.x);
        ay += (v0.y + v1.y) + (v2.y + v3.y);
        az += (v0.z + v1.z) + (v2.z + v3.z);
        aw += (v0.w + v1.w) + (v2.w + v3.w);
    }
    for (; e < e1; e += 4) {
        int s = col[e];
        float4 v = *(const float4*)(tyin + (size_t)s * 64 + fl * 4);
        ax += v.x; ay += v.y; az += v.z; aw += v.w;
    }
    // reduce across the 4 sub-groups (lanes sharing the same fl)
    #pragma unroll
    for (int off = 16; off <= 32; off <<= 1) {
        ax += __shfl_xor(ax, off, 64);
        ay += __shfl_xor(ay, off, 64);
        az += __shfl_xor(az, off, 64);
        aw += __shfl_xor(aw, off, 64);
    }
    float dr = dinv[wave];
    float cd = coeff[d];
    float tx_x = -dr * ax, tx_y = -dr * ay, tx_z = -dr * az, tx_w = -dr * aw;
    float4 o = *(const float4*)(out + (size_t)wave * 64 + fl * 4);
    o.x += cd * tx_x; o.y += cd * tx_y; o.z += cd * tx_z; o.w += cd * tx_w;
    if (!fuse_lsm) {
        if (sub == 0) {
            float4 ty;
            ty.x = dr * tx_x; ty.y = dr * tx_y; ty.z = dr * tx_z; ty.w = dr * tx_w;
            *(float4*)(tyout + (size_t)wave * 64 + fl * 4) = ty;
            *(float4*)(out + (size_t)wave * 64 + fl * 4) = o;
        }
    } else {
        // fused log_softmax over the 64-class row
        float m = fmaxf(fmaxf(o.x, o.y), fmaxf(o.z, o.w));
        #pragma unroll
        for (int off = 1; off < 16; off <<= 1) m = fmaxf(m, __shfl_xor(m, off, 64));
        float s4 = expf(o.x - m) + expf(o.y - m) + expf(o.z - m) + expf(o.w - m);
        #pragma unroll
        for (int off = 1; off < 16; off <<= 1) s4 += __shfl_xor(s4, off, 64);
        float lse = m + logf(s4);
        o.x -= lse; o.y -= lse; o.z -= lse; o.w -= lse;
        if (sub == 0)
            *(float4*)(out + (size_t)wave * 64 + fl * 4) = o;
    }
}

extern "C" void kernel_launch(void* const* d_in, const int* in_sizes, int n_in,
                              void* d_out, int out_size, void* d_ws, size_t ws_size,
                              hipStream_t stream) {
    const float* feature = (const float*)d_in[0];
    const int*   edges   = (const int*)d_in[1];
    const float* W1      = (const float*)d_in[2];
    const float* b1      = (const float*)d_in[3];
    const float* W2      = (const float*)d_in[4];
    const float* b2      = (const float*)d_in[5];
    const float* alpha   = (const float*)d_in[6];
    const float* beta    = (const float*)d_in[7];
    float* out = (float*)d_out;

    const int n = in_sizes[0] / FIN;      // 100000
    const int E = in_sizes[1] / 2;        // 3200000
    const int* src = edges;
    const int* dst = edges + E;

    // ---- workspace layout (256B aligned) ----
    char* ws = (char*)d_ws;
    size_t off = 0;
    auto alloc = [&](size_t bytes) { size_t o = off; off = (off + bytes + 255) & ~(size_t)255; return o; };
    float* coeff   = (float*)(ws + alloc(64 * 4));
    int*   deg     = (int*)  (ws + alloc((size_t)n * 4));
    int*   indeg   = (int*)  (ws + alloc((size_t)n * 4));
    float* dinv    = (float*)(ws + alloc((size_t)n * 4));
    int*   row_ptr = (int*)  (ws + alloc(((size_t)n + 1) * 4));
    int*   cursor  = (int*)  (ws + alloc((size_t)n * 4));
    int*   col     = (int*)  (ws + alloc((size_t)E * 4));
    float* H       = (float*)(ws + alloc((size_t)n * 64 * 4));
    float* TyA     = (float*)(ws + alloc((size_t)n * 64 * 4));
    float* TyB     = (float*)(ws + alloc((size_t)n * 64 * 4));

    // ---- host-side Taylor tables (deterministic, recomputed every call) ----
    Tables tb;
    for (int k = 0; k < KF; ++k) {
        double x = M_PI * (double)(k + 1);   // OMEGA = 1
        double p = 1.0, f = 1.0;
        for (int o = 0; o <= DORD; ++o) {
            if (o > 0) { p *= x; f *= (double)o; }
            double v = p / f;
            tb.cosc[k][o] = (o % 2 == 0) ? (float)((((o / 2) % 2 == 0) ? 1.0 : -1.0) * v) : 0.f;
            tb.sinc[k][o] = (o % 2 == 1) ? (float)(((((o - 1) / 2) % 2 == 0) ? 1.0 : -1.0) * v) : 0.f;
        }
    }

    hipMemsetAsync(deg, 0, (size_t)n * 4, stream);
    hipMemsetAsync(indeg, 0, (size_t)n * 4, stream);

    coeff_kernel<<<1, 64, 0, stream>>>(alpha, beta, tb, coeff);
    count_kernel<<<(E + 255) / 256, 256, 0, stream>>>(src, dst, deg, indeg, E);
    dinv_kernel<<<(n + 255) / 256, 256, 0, stream>>>(deg, dinv, n);
    scan_kernel<<<1, 1024, 0, stream>>>(indeg, row_ptr, cursor, n);
    fill_kernel<<<(E + 255) / 256, 256, 0, stream>>>(src, dst, cursor, col, E);

    gemm1_kernel<<<(n + 63) / 64, 256, 0, stream>>>(feature, W1, b1, H, n);
    gemm2_kernel<<<(n + 127) / 128, 256, 0, stream>>>(H, W2, b2, coeff, dinv, TyA, out, n);

    const float* tin = TyA;
    float* bufs[2] = { TyB, TyA };
    for (int d = 1; d <= DORD; ++d) {
        float* tout = bufs[(d - 1) & 1];
        spmm_kernel<<<(n + 3) / 4, 256, 0, stream>>>(row_ptr, col, dinv, tin, tout, out,
                                                     coeff, d, n, d == DORD ? 1 : 0);
        tin = tout;
    }
}

// Round 3
// 1877.891 us; speedup vs baseline: 1.2914x; 1.2119x over previous
//
#include <hip/hip_runtime.h>
#include <math.h>

#define NN 100000
#define FIN 500
#define HIDN 64
#define KF 5
#define DORD 10

typedef unsigned short ushort_t;

struct Tables { float sinc[KF][DORD+1]; float cosc[KF][DORD+1]; };

// bf16 helpers: low/high halves of a packed uint, RNE pack
__device__ inline float bl(unsigned u) { return __uint_as_float(u << 16); }
__device__ inline float bh(unsigned u) { return __uint_as_float(u & 0xffff0000u); }
__device__ inline unsigned short bf16_rne(float x) {
    unsigned u = __float_as_uint(x);
    return (unsigned short)((u + 0x7fffu + ((u >> 16) & 1u)) >> 16);
}
__device__ inline unsigned pack_bf16x2(float a, float b) {
    return (unsigned)bf16_rne(a) | ((unsigned)bf16_rne(b) << 16);
}

// ---- coeff[d] = sum_k alpha[k]*sinc[k][d] + beta[k]*cosc[k][d] ----
__global__ void coeff_kernel(const float* __restrict__ alpha, const float* __restrict__ beta,
                             Tables tb, float* __restrict__ coeff) {
    int d = threadIdx.x;
    if (d <= DORD) {
        float c = 0.f;
        #pragma unroll
        for (int k = 0; k < KF; ++k)
            c += alpha[k] * tb.sinc[k][d] + beta[k] * tb.cosc[k][d];
        coeff[d] = c;
    }
}

// ---- degree counting (out-deg by src for dinv, in-deg by dst for CSR) ----
__global__ void count_kernel(const int* __restrict__ src, const int* __restrict__ dst,
                             int* __restrict__ deg, int* __restrict__ indeg, int E) {
    int e = blockIdx.x * blockDim.x + threadIdx.x;
    if (e >= E) return;
    int s = src[e], d = dst[e];
    if (s != d) { atomicAdd(&deg[s], 1); atomicAdd(&indeg[d], 1); }
}

__global__ void dinv_kernel(const int* __restrict__ deg, float* __restrict__ dinv, int n) {
    int i = blockIdx.x * blockDim.x + threadIdx.x;
    if (i >= n) return;
    int d = deg[i];
    dinv[i] = (d > 0) ? (1.0f / sqrtf((float)d)) : 0.f;
}

// ---- single-block exclusive scan of indeg -> row_ptr (+cursor copy) ----
__global__ void scan_kernel(const int* __restrict__ indeg, int* __restrict__ row_ptr,
                            int* __restrict__ cursor, int n) {
    __shared__ int part[1024];
    int t = threadIdx.x;
    int chunk = (n + 1023) >> 10;
    int lo = t * chunk;
    int hi = lo + chunk; if (hi > n) hi = n;
    int s = 0;
    for (int i = lo; i < hi; ++i) s += indeg[i];
    part[t] = s;
    __syncthreads();
    for (int off = 1; off < 1024; off <<= 1) {
        int add = (t >= off) ? part[t - off] : 0;
        __syncthreads();
        part[t] += add;
        __syncthreads();
    }
    int run = (t > 0) ? part[t - 1] : 0;
    for (int i = lo; i < hi; ++i) {
        row_ptr[i] = run; cursor[i] = run;
        run += indeg[i];
    }
    if (t == 1023) row_ptr[n] = part[1023];
}

// ---- scatter edges into dst-CSR (col only; weights folded into dinv state) ----
__global__ void fill_kernel(const int* __restrict__ src, const int* __restrict__ dst,
                            int* __restrict__ cursor, int* __restrict__ col, int E) {
    int e = blockIdx.x * blockDim.x + threadIdx.x;
    if (e >= E) return;
    int s = src[e], d = dst[e];
    if (s == d) return;
    int pos = atomicAdd(&cursor[d], 1);
    col[pos] = s;
}

// ---- GEMM1: H = relu(A[n,500] @ W[500,64] + b) ----
__global__ __launch_bounds__(256) void gemm1_kernel(
    const float* __restrict__ A, const float* __restrict__ W,
    const float* __restrict__ bias, float* __restrict__ H, int n) {
    __shared__ float sA[64][36];   // row-major A tile, padded
    __shared__ float sW[32][64];
    int t = threadIdx.x;
    int tx = t & 15, ty = t >> 4;
    int rowBase = blockIdx.x * 64;
    float acc[4][4] = {{0.f}};
    for (int k0 = 0; k0 < FIN; k0 += 32) {
        #pragma unroll
        for (int l = 0; l < 2; ++l) {
            int c = t + l * 256;
            int r = c >> 3, cc = (c & 7) * 4;
            int gr = rowBase + r, gk = k0 + cc;
            float4 v = make_float4(0.f, 0.f, 0.f, 0.f);
            if (gr < n && gk < FIN) v = *(const float4*)(A + (size_t)gr * FIN + gk);
            *(float4*)&sA[r][cc] = v;
        }
        #pragma unroll
        for (int l = 0; l < 2; ++l) {
            int c = t + l * 256;
            int r = c >> 4, cc = (c & 15) * 4;
            int gk = k0 + r;
            float4 v = make_float4(0.f, 0.f, 0.f, 0.f);
            if (gk < FIN) v = *(const float4*)(W + (size_t)gk * 64 + cc);
            *(float4*)&sW[r][cc] = v;
        }
        __syncthreads();
        #pragma unroll
        for (int kk = 0; kk < 32; ++kk) {
            float a[4], b[4];
            #pragma unroll
            for (int i = 0; i < 4; ++i) a[i] = sA[ty * 4 + i][kk];
            #pragma unroll
            for (int j = 0; j < 4; ++j) b[j] = sW[kk][tx * 4 + j];
            #pragma unroll
            for (int i = 0; i < 4; ++i)
                #pragma unroll
                for (int j = 0; j < 4; ++j)
                    acc[i][j] = fmaf(a[i], b[j], acc[i][j]);
        }
        __syncthreads();
    }
    #pragma unroll
    for (int i = 0; i < 4; ++i) {
        int gr = rowBase + ty * 4 + i;
        if (gr < n) {
            float4 o;
            o.x = fmaxf(acc[i][0] + bias[tx * 4 + 0], 0.f);
            o.y = fmaxf(acc[i][1] + bias[tx * 4 + 1], 0.f);
            o.z = fmaxf(acc[i][2] + bias[tx * 4 + 2], 0.f);
            o.w = fmaxf(acc[i][3] + bias[tx * 4 + 3], 0.f);
            *(float4*)(H + (size_t)gr * 64 + tx * 4) = o;
        }
    }
}

// ---- GEMM2: X = H @ W2 + b2 ; out = (1+coeff[0])*X ; ty0 = bf16(dinv ⊙ X) ----
__global__ __launch_bounds__(256) void gemm2_kernel(
    const float* __restrict__ H, const float* __restrict__ W2,
    const float* __restrict__ b2, const float* __restrict__ coeff,
    const float* __restrict__ dinv, ushort_t* __restrict__ ty0,
    float* __restrict__ out, int n) {
    __shared__ float sW[64 * 64];
    __shared__ float sb[64];
    int t = threadIdx.x;
    for (int i = t; i < 4096; i += 256) sW[i] = W2[i];
    if (t < 64) sb[t] = b2[t];
    __syncthreads();
    float c0p1 = 1.f + coeff[0];
    int lane = t & 63;
    int wid = t >> 6;
    int r0 = blockIdx.x * 128;
    int rend = r0 + 128; if (rend > n) rend = n;
    for (int r = r0 + wid; r < rend; r += 4) {
        float hv = H[(size_t)r * 64 + lane];
        float dr = dinv[r];
        float acc = sb[lane];
        #pragma unroll
        for (int k = 0; k < 64; ++k)
            acc = fmaf(__shfl(hv, k, 64), sW[k * 64 + lane], acc);
        ty0[(size_t)r * 64 + lane] = bf16_rne(dr * acc);
        out[(size_t)r * 64 + lane] = c0p1 * acc;
    }
}

// ---- SpMM hop (dinv-folded, bf16 state): one wave per dst row.
// 16 lanes x 8B(bf16x4) per source row; 4 sub-groups -> 4 edges per wave-instr.
// Ty = bf16(dinv ⊙ Tx).  Tx_new[r] = -dinv[r] * Σ_{s∈N(r)} Ty[s]  (fp32 accum)
// tyout[r] = bf16(dinv[r]*Tx_new[r]);  out[r] += coeff[d]*Tx_new[r]  (fp32)
// fuse_lsm: final hop applies log_softmax to out instead of writing tyout.
__global__ __launch_bounds__(256) void spmm_kernel(
    const int* __restrict__ row_ptr, const int* __restrict__ col,
    const float* __restrict__ dinv, const ushort_t* __restrict__ tyin,
    ushort_t* __restrict__ tyout, float* __restrict__ out,
    const float* __restrict__ coeff, int d, int n, int fuse_lsm) {
    int wave = (blockIdx.x * blockDim.x + threadIdx.x) >> 6;
    if (wave >= n) return;
    int lane = threadIdx.x & 63;
    int sub = lane >> 4;       // 0..3: which edge within a group of 4
    int fl = lane & 15;        // feature group: elems 4*fl .. 4*fl+3
    int e0 = row_ptr[wave], e1 = row_ptr[wave + 1];
    float ax = 0.f, ay = 0.f, az = 0.f, aw = 0.f;
    int e = e0 + sub;
    for (; e + 12 < e1; e += 16) {
        int s0 = col[e], s1 = col[e + 4], s2 = col[e + 8], s3 = col[e + 12];
        uint2 p0 = *(const uint2*)(tyin + (size_t)s0 * 64 + fl * 4);
        uint2 p1 = *(const uint2*)(tyin + (size_t)s1 * 64 + fl * 4);
        uint2 p2 = *(const uint2*)(tyin + (size_t)s2 * 64 + fl * 4);
        uint2 p3 = *(const uint2*)(tyin + (size_t)s3 * 64 + fl * 4);
        ax += (bl(p0.x) + bl(p1.x)) + (bl(p2.x) + bl(p3.x));
        ay += (bh(p0.x) + bh(p1.x)) + (bh(p2.x) + bh(p3.x));
        az += (bl(p0.y) + bl(p1.y)) + (bl(p2.y) + bl(p3.y));
        aw += (bh(p0.y) + bh(p1.y)) + (bh(p2.y) + bh(p3.y));
    }
    for (; e < e1; e += 4) {
        int s = col[e];
        uint2 p = *(const uint2*)(tyin + (size_t)s * 64 + fl * 4);
        ax += bl(p.x); ay += bh(p.x); az += bl(p.y); aw += bh(p.y);
    }
    // reduce across the 4 sub-groups (lanes sharing the same fl)
    #pragma unroll
    for (int off = 16; off <= 32; off <<= 1) {
        ax += __shfl_xor(ax, off, 64);
        ay += __shfl_xor(ay, off, 64);
        az += __shfl_xor(az, off, 64);
        aw += __shfl_xor(aw, off, 64);
    }
    float dr = dinv[wave];
    float cd = coeff[d];
    float tx_x = -dr * ax, tx_y = -dr * ay, tx_z = -dr * az, tx_w = -dr * aw;
    float4 o = *(const float4*)(out + (size_t)wave * 64 + fl * 4);
    o.x += cd * tx_x; o.y += cd * tx_y; o.z += cd * tx_z; o.w += cd * tx_w;
    if (!fuse_lsm) {
        if (sub == 0) {
            uint2 ty;
            ty.x = pack_bf16x2(dr * tx_x, dr * tx_y);
            ty.y = pack_bf16x2(dr * tx_z, dr * tx_w);
            *(uint2*)(tyout + (size_t)wave * 64 + fl * 4) = ty;
            *(float4*)(out + (size_t)wave * 64 + fl * 4) = o;
        }
    } else {
        // fused log_softmax over the 64-class row
        float m = fmaxf(fmaxf(o.x, o.y), fmaxf(o.z, o.w));
        #pragma unroll
        for (int off = 1; off < 16; off <<= 1) m = fmaxf(m, __shfl_xor(m, off, 64));
        float s4 = expf(o.x - m) + expf(o.y - m) + expf(o.z - m) + expf(o.w - m);
        #pragma unroll
        for (int off = 1; off < 16; off <<= 1) s4 += __shfl_xor(s4, off, 64);
        float lse = m + logf(s4);
        o.x -= lse; o.y -= lse; o.z -= lse; o.w -= lse;
        if (sub == 0)
            *(float4*)(out + (size_t)wave * 64 + fl * 4) = o;
    }
}

extern "C" void kernel_launch(void* const* d_in, const int* in_sizes, int n_in,
                              void* d_out, int out_size, void* d_ws, size_t ws_size,
                              hipStream_t stream) {
    const float* feature = (const float*)d_in[0];
    const int*   edges   = (const int*)d_in[1];
    const float* W1      = (const float*)d_in[2];
    const float* b1      = (const float*)d_in[3];
    const float* W2      = (const float*)d_in[4];
    const float* b2      = (const float*)d_in[5];
    const float* alpha   = (const float*)d_in[6];
    const float* beta    = (const float*)d_in[7];
    float* out = (float*)d_out;

    const int n = in_sizes[0] / FIN;      // 100000
    const int E = in_sizes[1] / 2;        // 3200000
    const int* src = edges;
    const int* dst = edges + E;

    // ---- workspace layout (256B aligned) ----
    char* ws = (char*)d_ws;
    size_t off = 0;
    auto alloc = [&](size_t bytes) { size_t o = off; off = (off + bytes + 255) & ~(size_t)255; return o; };
    float*    coeff   = (float*)   (ws + alloc(64 * 4));
    int*      deg     = (int*)     (ws + alloc((size_t)n * 4));
    int*      indeg   = (int*)     (ws + alloc((size_t)n * 4));
    float*    dinv    = (float*)   (ws + alloc((size_t)n * 4));
    int*      row_ptr = (int*)     (ws + alloc(((size_t)n + 1) * 4));
    int*      cursor  = (int*)     (ws + alloc((size_t)n * 4));
    int*      col     = (int*)     (ws + alloc((size_t)E * 4));
    float*    H       = (float*)   (ws + alloc((size_t)n * 64 * 4));
    ushort_t* TyA     = (ushort_t*)(ws + alloc((size_t)n * 64 * 2));
    ushort_t* TyB     = (ushort_t*)(ws + alloc((size_t)n * 64 * 2));

    // ---- host-side Taylor tables (deterministic, recomputed every call) ----
    Tables tb;
    for (int k = 0; k < KF; ++k) {
        double x = M_PI * (double)(k + 1);   // OMEGA = 1
        double p = 1.0, f = 1.0;
        for (int o = 0; o <= DORD; ++o) {
            if (o > 0) { p *= x; f *= (double)o; }
            double v = p / f;
            tb.cosc[k][o] = (o % 2 == 0) ? (float)((((o / 2) % 2 == 0) ? 1.0 : -1.0) * v) : 0.f;
            tb.sinc[k][o] = (o % 2 == 1) ? (float)(((((o - 1) / 2) % 2 == 0) ? 1.0 : -1.0) * v) : 0.f;
        }
    }

    hipMemsetAsync(deg, 0, (size_t)n * 4, stream);
    hipMemsetAsync(indeg, 0, (size_t)n * 4, stream);

    coeff_kernel<<<1, 64, 0, stream>>>(alpha, beta, tb, coeff);
    count_kernel<<<(E + 255) / 256, 256, 0, stream>>>(src, dst, deg, indeg, E);
    dinv_kernel<<<(n + 255) / 256, 256, 0, stream>>>(deg, dinv, n);
    scan_kernel<<<1, 1024, 0, stream>>>(indeg, row_ptr, cursor, n);
    fill_kernel<<<(E + 255) / 256, 256, 0, stream>>>(src, dst, cursor, col, E);

    gemm1_kernel<<<(n + 63) / 64, 256, 0, stream>>>(feature, W1, b1, H, n);
    gemm2_kernel<<<(n + 127) / 128, 256, 0, stream>>>(H, W2, b2, coeff, dinv, TyA, out, n);

    const ushort_t* tin = TyA;
    ushort_t* bufs[2] = { TyB, TyA };
    for (int d = 1; d <= DORD; ++d) {
        ushort_t* tout = bufs[(d - 1) & 1];
        spmm_kernel<<<(n + 3) / 4, 256, 0, stream>>>(row_ptr, col, dinv, tin, tout, out,
                                                     coeff, d, n, d == DORD ? 1 : 0);
        tin = tout;
    }
}

// Round 4
// 1353.061 us; speedup vs baseline: 1.7923x; 1.3879x over previous
//
#include <hip/hip_runtime.h>
#include <math.h>

#define NN 100000
#define FIN 500
#define HIDN 64
#define KF 5
#define DORD 10

typedef unsigned short ushort_t;

struct Tables { float sinc[KF][DORD+1]; float cosc[KF][DORD+1]; };

// bf16 helpers: low/high halves of a packed uint, RNE pack
__device__ inline float bl(unsigned u) { return __uint_as_float(u << 16); }
__device__ inline float bh(unsigned u) { return __uint_as_float(u & 0xffff0000u); }
__device__ inline unsigned short bf16_rne(float x) {
    unsigned u = __float_as_uint(x);
    return (unsigned short)((u + 0x7fffu + ((u >> 16) & 1u)) >> 16);
}
__device__ inline unsigned pack_bf16x2(float a, float b) {
    return (unsigned)bf16_rne(a) | ((unsigned)bf16_rne(b) << 16);
}

// ---- coeff[d] = sum_k alpha[k]*sinc[k][d] + beta[k]*cosc[k][d] ----
__global__ void coeff_kernel(const float* __restrict__ alpha, const float* __restrict__ beta,
                             Tables tb, float* __restrict__ coeff) {
    int d = threadIdx.x;
    if (d <= DORD) {
        float c = 0.f;
        #pragma unroll
        for (int k = 0; k < KF; ++k)
            c += alpha[k] * tb.sinc[k][d] + beta[k] * tb.cosc[k][d];
        coeff[d] = c;
    }
}

// ---- pass 0: dst-bucket histogram (LDS-privatized) + out-degree atomics ----
#define CHUNK 8192
__global__ __launch_bounds__(256) void bin_hist_kernel(
    const int* __restrict__ src, const int* __restrict__ dst,
    int* __restrict__ deg, int* __restrict__ bucket_cnt,
    int E, int drng, int nb) {
    __shared__ int h[512];
    for (int i = threadIdx.x; i < nb; i += 256) h[i] = 0;
    __syncthreads();
    int base = blockIdx.x * CHUNK;
    int end = base + CHUNK; if (end > E) end = E;
    for (int e = base + threadIdx.x; e < end; e += 256) {
        int s = src[e], d = dst[e];
        if (s != d) {
            atomicAdd(&deg[s], 1);
            atomicAdd(&h[d / drng], 1);
        }
    }
    __syncthreads();
    for (int i = threadIdx.x; i < nb; i += 256)
        if (h[i]) atomicAdd(&bucket_cnt[i], h[i]);
}

__global__ void dinv_kernel(const int* __restrict__ deg, float* __restrict__ dinv, int n) {
    int i = blockIdx.x * blockDim.x + threadIdx.x;
    if (i >= n) return;
    int d = deg[i];
    dinv[i] = (d > 0) ? (1.0f / sqrtf((float)d)) : 0.f;
}

// ---- scan of bucket counts -> bucket_off (+cursor copy) ----
__global__ void bucket_scan_kernel(const int* __restrict__ bucket_cnt,
                                   int* __restrict__ bucket_off,
                                   int* __restrict__ bucket_cur, int nb) {
    __shared__ int tmp[512];
    int t = threadIdx.x;
    tmp[t] = (t < nb) ? bucket_cnt[t] : 0;
    __syncthreads();
    for (int off = 1; off < 512; off <<= 1) {
        int add = (t >= off) ? tmp[t - off] : 0;
        __syncthreads();
        tmp[t] += add;
        __syncthreads();
    }
    int excl = (t > 0) ? tmp[t - 1] : 0;
    if (t < nb) { bucket_off[t] = excl; bucket_cur[t] = excl; }
    if (t == nb - 1) bucket_off[nb] = tmp[t];
}

// ---- pass 1: block-local LDS binning scatter of (src,dst) pairs ----
__global__ __launch_bounds__(256) void bin_scatter_kernel(
    const int* __restrict__ src, const int* __restrict__ dst,
    int* __restrict__ bucket_cur, uint2* __restrict__ binned,
    int E, int drng, int nb) {
    __shared__ int h[512];
    for (int i = threadIdx.x; i < nb; i += 256) h[i] = 0;
    __syncthreads();
    int base = blockIdx.x * CHUNK;
    int end = base + CHUNK; if (end > E) end = E;
    // phase A: block-local bucket counts
    for (int e = base + threadIdx.x; e < end; e += 256) {
        int s = src[e], d = dst[e];
        if (s != d) atomicAdd(&h[d / drng], 1);
    }
    __syncthreads();
    // phase B: reserve global ranges, h becomes absolute running cursor
    for (int i = threadIdx.x; i < nb; i += 256) {
        int c = h[i];
        h[i] = c ? atomicAdd(&bucket_cur[i], c) : 0;
    }
    __syncthreads();
    // phase C: scatter (all writes from this CU land in ~contiguous bursts)
    for (int e = base + threadIdx.x; e < end; e += 256) {
        int s = src[e], d = dst[e];
        if (s != d) {
            int pos = atomicAdd(&h[d / drng], 1);
            binned[pos] = make_uint2((unsigned)s, (unsigned)d);
        }
    }
}

// ---- pass 2: one block owns one bucket: local indeg, scan, row_ptr, col ----
__global__ __launch_bounds__(256) void bucket_csr_kernel(
    const uint2* __restrict__ binned, const int* __restrict__ bucket_off,
    int* __restrict__ row_ptr, int* __restrict__ col,
    int n, int drng, int nb) {
    int b = blockIdx.x;
    int e0 = bucket_off[b], e1 = bucket_off[b + 1];
    int d0 = b * drng;
    int dn = n - d0; if (dn > drng) dn = drng;
    __shared__ int ind[256];
    __shared__ int cur[256];
    int t = threadIdx.x;
    ind[t] = 0;
    __syncthreads();
    for (int e = e0 + t; e < e1; e += 256) {
        uint2 p = binned[e];
        atomicAdd(&ind[(int)p.y - d0], 1);
    }
    __syncthreads();
    // inclusive scan over 256 entries
    for (int off = 1; off < 256; off <<= 1) {
        int add = (t >= off) ? ind[t - off] : 0;
        __syncthreads();
        ind[t] += add;
        __syncthreads();
    }
    if (t < dn) {
        int excl = (t > 0) ? ind[t - 1] : 0;
        row_ptr[d0 + t] = e0 + excl;
        cur[t] = e0 + excl;
    }
    if (b == 0 && t == 0) row_ptr[n] = bucket_off[nb];
    __syncthreads();
    for (int e = e0 + t; e < e1; e += 256) {
        uint2 p = binned[e];
        int pos = atomicAdd(&cur[(int)p.y - d0], 1);
        col[pos] = (int)p.x;
    }
}

// ---- GEMM1: H = relu(A[n,500] @ W[500,64] + b) ----
__global__ __launch_bounds__(256) void gemm1_kernel(
    const float* __restrict__ A, const float* __restrict__ W,
    const float* __restrict__ bias, float* __restrict__ H, int n) {
    __shared__ float sA[64][36];   // row-major A tile, padded
    __shared__ float sW[32][64];
    int t = threadIdx.x;
    int tx = t & 15, ty = t >> 4;
    int rowBase = blockIdx.x * 64;
    float acc[4][4] = {{0.f}};
    for (int k0 = 0; k0 < FIN; k0 += 32) {
        #pragma unroll
        for (int l = 0; l < 2; ++l) {
            int c = t + l * 256;
            int r = c >> 3, cc = (c & 7) * 4;
            int gr = rowBase + r, gk = k0 + cc;
            float4 v = make_float4(0.f, 0.f, 0.f, 0.f);
            if (gr < n && gk < FIN) v = *(const float4*)(A + (size_t)gr * FIN + gk);
            *(float4*)&sA[r][cc] = v;
        }
        #pragma unroll
        for (int l = 0; l < 2; ++l) {
            int c = t + l * 256;
            int r = c >> 4, cc = (c & 15) * 4;
            int gk = k0 + r;
            float4 v = make_float4(0.f, 0.f, 0.f, 0.f);
            if (gk < FIN) v = *(const float4*)(W + (size_t)gk * 64 + cc);
            *(float4*)&sW[r][cc] = v;
        }
        __syncthreads();
        #pragma unroll
        for (int kk = 0; kk < 32; ++kk) {
            float a[4], b[4];
            #pragma unroll
            for (int i = 0; i < 4; ++i) a[i] = sA[ty * 4 + i][kk];
            #pragma unroll
            for (int j = 0; j < 4; ++j) b[j] = sW[kk][tx * 4 + j];
            #pragma unroll
            for (int i = 0; i < 4; ++i)
                #pragma unroll
                for (int j = 0; j < 4; ++j)
                    acc[i][j] = fmaf(a[i], b[j], acc[i][j]);
        }
        __syncthreads();
    }
    #pragma unroll
    for (int i = 0; i < 4; ++i) {
        int gr = rowBase + ty * 4 + i;
        if (gr < n) {
            float4 o;
            o.x = fmaxf(acc[i][0] + bias[tx * 4 + 0], 0.f);
            o.y = fmaxf(acc[i][1] + bias[tx * 4 + 1], 0.f);
            o.z = fmaxf(acc[i][2] + bias[tx * 4 + 2], 0.f);
            o.w = fmaxf(acc[i][3] + bias[tx * 4 + 3], 0.f);
            *(float4*)(H + (size_t)gr * 64 + tx * 4) = o;
        }
    }
}

// ---- GEMM2: X = H @ W2 + b2 ; out = (1+coeff[0])*X ; ty0 = bf16(dinv ⊙ X) ----
__global__ __launch_bounds__(256) void gemm2_kernel(
    const float* __restrict__ H, const float* __restrict__ W2,
    const float* __restrict__ b2, const float* __restrict__ coeff,
    const float* __restrict__ dinv, ushort_t* __restrict__ ty0,
    float* __restrict__ out, int n) {
    __shared__ float sW[64 * 64];
    __shared__ float sb[64];
    int t = threadIdx.x;
    for (int i = t; i < 4096; i += 256) sW[i] = W2[i];
    if (t < 64) sb[t] = b2[t];
    __syncthreads();
    float c0p1 = 1.f + coeff[0];
    int lane = t & 63;
    int wid = t >> 6;
    int r0 = blockIdx.x * 128;
    int rend = r0 + 128; if (rend > n) rend = n;
    for (int r = r0 + wid; r < rend; r += 4) {
        float hv = H[(size_t)r * 64 + lane];
        float dr = dinv[r];
        float acc = sb[lane];
        #pragma unroll
        for (int k = 0; k < 64; ++k)
            acc = fmaf(__shfl(hv, k, 64), sW[k * 64 + lane], acc);
        ty0[(size_t)r * 64 + lane] = bf16_rne(dr * acc);
        out[(size_t)r * 64 + lane] = c0p1 * acc;
    }
}

// ---- SpMM hop (dinv-folded, bf16 state): one wave per dst row.
__global__ __launch_bounds__(256) void spmm_kernel(
    const int* __restrict__ row_ptr, const int* __restrict__ col,
    const float* __restrict__ dinv, const ushort_t* __restrict__ tyin,
    ushort_t* __restrict__ tyout, float* __restrict__ out,
    const float* __restrict__ coeff, int d, int n, int fuse_lsm) {
    int wave = (blockIdx.x * blockDim.x + threadIdx.x) >> 6;
    if (wave >= n) return;
    int lane = threadIdx.x & 63;
    int sub = lane >> 4;       // 0..3: which edge within a group of 4
    int fl = lane & 15;        // feature group: elems 4*fl .. 4*fl+3
    int e0 = row_ptr[wave], e1 = row_ptr[wave + 1];
    float ax = 0.f, ay = 0.f, az = 0.f, aw = 0.f;
    int e = e0 + sub;
    for (; e + 12 < e1; e += 16) {
        int s0 = col[e], s1 = col[e + 4], s2 = col[e + 8], s3 = col[e + 12];
        uint2 p0 = *(const uint2*)(tyin + (size_t)s0 * 64 + fl * 4);
        uint2 p1 = *(const uint2*)(tyin + (size_t)s1 * 64 + fl * 4);
        uint2 p2 = *(const uint2*)(tyin + (size_t)s2 * 64 + fl * 4);
        uint2 p3 = *(const uint2*)(tyin + (size_t)s3 * 64 + fl * 4);
        ax += (bl(p0.x) + bl(p1.x)) + (bl(p2.x) + bl(p3.x));
        ay += (bh(p0.x) + bh(p1.x)) + (bh(p2.x) + bh(p3.x));
        az += (bl(p0.y) + bl(p1.y)) + (bl(p2.y) + bl(p3.y));
        aw += (bh(p0.y) + bh(p1.y)) + (bh(p2.y) + bh(p3.y));
    }
    for (; e < e1; e += 4) {
        int s = col[e];
        uint2 p = *(const uint2*)(tyin + (size_t)s * 64 + fl * 4);
        ax += bl(p.x); ay += bh(p.x); az += bl(p.y); aw += bh(p.y);
    }
    #pragma unroll
    for (int off = 16; off <= 32; off <<= 1) {
        ax += __shfl_xor(ax, off, 64);
        ay += __shfl_xor(ay, off, 64);
        az += __shfl_xor(az, off, 64);
        aw += __shfl_xor(aw, off, 64);
    }
    float dr = dinv[wave];
    float cd = coeff[d];
    float tx_x = -dr * ax, tx_y = -dr * ay, tx_z = -dr * az, tx_w = -dr * aw;
    float4 o = *(const float4*)(out + (size_t)wave * 64 + fl * 4);
    o.x += cd * tx_x; o.y += cd * tx_y; o.z += cd * tx_z; o.w += cd * tx_w;
    if (!fuse_lsm) {
        if (sub == 0) {
            uint2 ty;
            ty.x = pack_bf16x2(dr * tx_x, dr * tx_y);
            ty.y = pack_bf16x2(dr * tx_z, dr * tx_w);
            *(uint2*)(tyout + (size_t)wave * 64 + fl * 4) = ty;
            *(float4*)(out + (size_t)wave * 64 + fl * 4) = o;
        }
    } else {
        float m = fmaxf(fmaxf(o.x, o.y), fmaxf(o.z, o.w));
        #pragma unroll
        for (int off = 1; off < 16; off <<= 1) m = fmaxf(m, __shfl_xor(m, off, 64));
        float s4 = expf(o.x - m) + expf(o.y - m) + expf(o.z - m) + expf(o.w - m);
        #pragma unroll
        for (int off = 1; off < 16; off <<= 1) s4 += __shfl_xor(s4, off, 64);
        float lse = m + logf(s4);
        o.x -= lse; o.y -= lse; o.z -= lse; o.w -= lse;
        if (sub == 0)
            *(float4*)(out + (size_t)wave * 64 + fl * 4) = o;
    }
}

extern "C" void kernel_launch(void* const* d_in, const int* in_sizes, int n_in,
                              void* d_out, int out_size, void* d_ws, size_t ws_size,
                              hipStream_t stream) {
    const float* feature = (const float*)d_in[0];
    const int*   edges   = (const int*)d_in[1];
    const float* W1      = (const float*)d_in[2];
    const float* b1      = (const float*)d_in[3];
    const float* W2      = (const float*)d_in[4];
    const float* b2      = (const float*)d_in[5];
    const float* alpha   = (const float*)d_in[6];
    const float* beta    = (const float*)d_in[7];
    float* out = (float*)d_out;

    const int n = in_sizes[0] / FIN;      // 100000
    const int E = in_sizes[1] / 2;        // 3200000
    const int* src = edges;
    const int* dst = edges + E;

    const int drng = (n + 511) / 512;             // 196 dsts per bucket
    const int nb   = (n + drng - 1) / drng;       // 511 buckets

    // ---- workspace layout (256B aligned) ----
    char* ws = (char*)d_ws;
    size_t off = 0;
    auto alloc = [&](size_t bytes) { size_t o = off; off = (off + bytes + 255) & ~(size_t)255; return o; };
    float*    coeff      = (float*)   (ws + alloc(64 * 4));
    int*      deg        = (int*)     (ws + alloc((size_t)n * 4));
    float*    dinv       = (float*)   (ws + alloc((size_t)n * 4));
    int*      row_ptr    = (int*)     (ws + alloc(((size_t)n + 1) * 4));
    int*      bucket_cnt = (int*)     (ws + alloc(512 * 4));
    int*      bucket_off = (int*)     (ws + alloc(513 * 4));
    int*      bucket_cur = (int*)     (ws + alloc(512 * 4));
    int*      col        = (int*)     (ws + alloc((size_t)E * 4));
    uint2*    binned     = (uint2*)   (ws + alloc((size_t)E * 8));
    float*    H          = (float*)   (ws + alloc((size_t)n * 64 * 4));
    ushort_t* TyA        = (ushort_t*)(ws + alloc((size_t)n * 64 * 2));
    ushort_t* TyB        = (ushort_t*)(ws + alloc((size_t)n * 64 * 2));

    // ---- host-side Taylor tables (deterministic, recomputed every call) ----
    Tables tb;
    for (int k = 0; k < KF; ++k) {
        double x = M_PI * (double)(k + 1);   // OMEGA = 1
        double p = 1.0, f = 1.0;
        for (int o = 0; o <= DORD; ++o) {
            if (o > 0) { p *= x; f *= (double)o; }
            double v = p / f;
            tb.cosc[k][o] = (o % 2 == 0) ? (float)((((o / 2) % 2 == 0) ? 1.0 : -1.0) * v) : 0.f;
            tb.sinc[k][o] = (o % 2 == 1) ? (float)(((((o - 1) / 2) % 2 == 0) ? 1.0 : -1.0) * v) : 0.f;
        }
    }

    hipMemsetAsync(deg, 0, (size_t)n * 4, stream);
    hipMemsetAsync(bucket_cnt, 0, 512 * 4, stream);

    coeff_kernel<<<1, 64, 0, stream>>>(alpha, beta, tb, coeff);

    int nchunk = (E + CHUNK - 1) / CHUNK;
    bin_hist_kernel<<<nchunk, 256, 0, stream>>>(src, dst, deg, bucket_cnt, E, drng, nb);
    dinv_kernel<<<(n + 255) / 256, 256, 0, stream>>>(deg, dinv, n);
    bucket_scan_kernel<<<1, 512, 0, stream>>>(bucket_cnt, bucket_off, bucket_cur, nb);
    bin_scatter_kernel<<<nchunk, 256, 0, stream>>>(src, dst, bucket_cur, binned, E, drng, nb);
    bucket_csr_kernel<<<nb, 256, 0, stream>>>(binned, bucket_off, row_ptr, col, n, drng, nb);

    gemm1_kernel<<<(n + 63) / 64, 256, 0, stream>>>(feature, W1, b1, H, n);
    gemm2_kernel<<<(n + 127) / 128, 256, 0, stream>>>(H, W2, b2, coeff, dinv, TyA, out, n);

    const ushort_t* tin = TyA;
    ushort_t* bufs[2] = { TyB, TyA };
    for (int d = 1; d <= DORD; ++d) {
        ushort_t* tout = bufs[(d - 1) & 1];
        spmm_kernel<<<(n + 3) / 4, 256, 0, stream>>>(row_ptr, col, dinv, tin, tout, out,
                                                     coeff, d, n, d == DORD ? 1 : 0);
        tin = tout;
    }
}